// Round 3
// baseline (181.789 us; speedup 1.0000x reference)
//
#include <hip/hip_runtime.h>
#include <hip/hip_bf16.h>
#include <stdint.h>

#define B_    32
#define CIN   128
#define COUT  128
#define KEXP  4
#define HW_   12544   // 112*112

typedef __attribute__((ext_vector_type(8))) short bf16x8;
typedef __attribute__((ext_vector_type(4))) float f32x4;

// fp32 -> bf16 round-to-nearest-even (inputs finite, no NaN handling)
static __device__ __forceinline__ ushort f2bf(float f) {
    uint32_t u = __builtin_bit_cast(uint32_t, f);
    u += 0x7FFFu + ((u >> 16) & 1u);
    return (ushort)(u >> 16);
}

// ---------------------------------------------------------------------------
// Kernel 1: pooled[b][i] = mean_{hw} x[b][i][hw].  One block per (b,i) row.
// Normal (caching) loads on purpose: warms L3 with x for conv_kernel.
// ---------------------------------------------------------------------------
__global__ __launch_bounds__(256) void pool_kernel(const float* __restrict__ x,
                                                   float* __restrict__ pooled) {
    const int row = blockIdx.x;                 // b*128 + i
    const float4* __restrict__ x4 = (const float4*)(x + (size_t)row * HW_);
    const int t = threadIdx.x;
    float s = 0.f;
    for (int idx = t; idx < HW_ / 4; idx += 256) {   // 3136 float4
        float4 v = x4[idx];
        s += (v.x + v.y) + (v.z + v.w);
    }
    #pragma unroll
    for (int off = 32; off > 0; off >>= 1) s += __shfl_down(s, off, 64);
    __shared__ float wsum[4];
    if ((t & 63) == 0) wsum[t >> 6] = s;
    __syncthreads();
    if (t == 0) pooled[row] = (wsum[0] + wsum[1] + wsum[2] + wsum[3]) * (1.0f / HW_);
}

// ---------------------------------------------------------------------------
// Kernel 2: gate (softmax over K=4) + combine expert weights -> bf16 w_mix.
// One block per batch sample.
// ---------------------------------------------------------------------------
__global__ __launch_bounds__(256) void gate_kernel(const float* __restrict__ pooled,
                                                   const float* __restrict__ gate_w,
                                                   const float* __restrict__ gate_b,
                                                   const float* __restrict__ expert_w,
                                                   short* __restrict__ wmix) {
    const int b = blockIdx.x;
    const int t = threadIdx.x;
    const int wid = t >> 6, lane = t & 63;
    __shared__ float logits[KEXP];
    __shared__ float gsh[KEXP];
    {
        float p0 = pooled[b * CIN + lane];
        float p1 = pooled[b * CIN + 64 + lane];
        float s = p0 * gate_w[wid * CIN + lane] + p1 * gate_w[wid * CIN + 64 + lane];
        #pragma unroll
        for (int off = 32; off > 0; off >>= 1) s += __shfl_down(s, off, 64);
        if (lane == 0) logits[wid] = s + gate_b[wid];
    }
    __syncthreads();
    if (t == 0) {
        float m = fmaxf(fmaxf(logits[0], logits[1]), fmaxf(logits[2], logits[3]));
        float e0 = expf(logits[0] - m), e1 = expf(logits[1] - m);
        float e2 = expf(logits[2] - m), e3 = expf(logits[3] - m);
        float inv = 1.f / (e0 + e1 + e2 + e3);
        gsh[0] = e0 * inv; gsh[1] = e1 * inv; gsh[2] = e2 * inv; gsh[3] = e3 * inv;
    }
    __syncthreads();
    const float g0 = gsh[0], g1 = gsh[1], g2 = gsh[2], g3 = gsh[3];
    for (int idx = t; idx < COUT * CIN; idx += 256) {
        float w = g0 * expert_w[idx]
                + g1 * expert_w[COUT * CIN + idx]
                + g2 * expert_w[2 * COUT * CIN + idx]
                + g3 * expert_w[3 * COUT * CIN + idx];
        wmix[b * COUT * CIN + idx] = (short)f2bf(w);
    }
}

// ---------------------------------------------------------------------------
// Kernel 3: out[b] = w_mix[b] (128x128) @ x[b] (128x12544), bf16 MFMA.
// Block = 4 waves, 64 pixels. A = X-tile (M=pix) from LDS (XOR-swizzled,
// staged via coalesced float4 + reg transpose). B = W fragments loaded
// DIRECTLY from global (wmix[b] is 32KB, L2-resident across the 196 blocks
// of a batch) — no W LDS staging. LDS = 16KB -> 4 blocks/CU with
// __launch_bounds__(256,4). Stores nontemporal f32x4 (pixel-contiguous).
// ---------------------------------------------------------------------------
__global__ __launch_bounds__(256, 4) void conv_kernel(const float* __restrict__ x,
                                                      const short* __restrict__ wmix,
                                                      float* __restrict__ out) {
    __shared__ char xlds[64 * 256];             // 64 rows (pix) x 256B (128 cin bf16), swizzled
    const int b  = blockIdx.y;
    const int p0 = blockIdx.x * 64;
    const int t  = threadIdx.x;

    // ---- stage X tile [128 cin][64 pix] -> xlds[pix][cin] bf16, swizzled ----
    {
        const int pg = t & 15;                  // pixel 4-group
        const int cg = t >> 4;                  // cin 4-group within pass
        #pragma unroll
        for (int p = 0; p < 2; ++p) {
            const int cin0 = p * 64 + cg * 4;
            const float* xrow = x + (size_t)b * CIN * HW_ + (size_t)cin0 * HW_ + p0 + pg * 4;
            float va[4][4];
            #pragma unroll
            for (int i = 0; i < 4; ++i) {
                float4 v = *(const float4*)(xrow + (size_t)i * HW_);
                va[i][0] = v.x; va[i][1] = v.y; va[i][2] = v.z; va[i][3] = v.w;
            }
            #pragma unroll
            for (int j = 0; j < 4; ++j) {
                const int pix = pg * 4 + j;
                uint32_t lo = (uint32_t)f2bf(va[0][j]) | ((uint32_t)f2bf(va[1][j]) << 16);
                uint32_t hi = (uint32_t)f2bf(va[2][j]) | ((uint32_t)f2bf(va[3][j]) << 16);
                int byte = (pix * 256 + cin0 * 2) ^ ((pix & 7) << 4);
                uint2 w2; w2.x = lo; w2.y = hi;
                *(uint2*)(xlds + byte) = w2;
            }
        }
    }

    const int wave = t >> 6;
    const int lane = t & 63;
    const int n = lane & 15;                    // MFMA row/col within 16
    const int h = lane >> 4;                    // k-octet selector

    // per-lane W fragment base: wmix[b][cout=n][cin=h*8]
    const short* __restrict__ wb = wmix + (size_t)b * COUT * CIN + n * CIN + h * 8;

    __syncthreads();

    // ---- A fragments: this lane's pixel row, 4 k-chunks (hoisted) ----
    bf16x8 xfrag[4];
    {
        const int pixl = wave * 16 + n;
        #pragma unroll
        for (int kk = 0; kk < 4; ++kk) {
            int byte = (pixl * 256 + kk * 64 + h * 16) ^ ((pixl & 7) << 4);
            xfrag[kk] = *(const bf16x8*)(xlds + byte);
        }
    }

    f32x4 acc[8];
    #pragma unroll
    for (int ot = 0; ot < 8; ++ot) acc[ot] = (f32x4){0.f, 0.f, 0.f, 0.f};

    // ---- K-loop: 8 cout tiles of 16; inner 4 chunks of 32 cin; W from L2 ----
    #pragma unroll
    for (int ot = 0; ot < 8; ++ot) {
        #pragma unroll
        for (int kk = 0; kk < 4; ++kk) {
            bf16x8 wfrag = *(const bf16x8*)(wb + (size_t)ot * 16 * CIN + kk * 32);
            acc[ot] = __builtin_amdgcn_mfma_f32_16x16x32_bf16(xfrag[kk], wfrag, acc[ot], 0, 0, 0);
        }
    }

    // ---- epilogue: col(lane&15)=cout, row=(lane>>4)*4+r = pixel -> float4 nt store ----
    float* __restrict__ ob = out + (size_t)b * COUT * HW_ + p0 + wave * 16 + h * 4;
    #pragma unroll
    for (int ot = 0; ot < 8; ++ot) {
        int cout = ot * 16 + n;
        __builtin_nontemporal_store(acc[ot], (f32x4*)(ob + (size_t)cout * HW_));
    }
}

// ---------------------------------------------------------------------------
extern "C" void kernel_launch(void* const* d_in, const int* in_sizes, int n_in,
                              void* d_out, int out_size, void* d_ws, size_t ws_size,
                              hipStream_t stream) {
    const float* x        = (const float*)d_in[0];
    const float* expert_w = (const float*)d_in[1];
    const float* gate_w   = (const float*)d_in[2];
    const float* gate_b   = (const float*)d_in[3];
    float* out = (float*)d_out;

    float* pooled = (float*)d_ws;                          // 32*128 fp32 = 16 KB
    short* wmix   = (short*)((char*)d_ws + 16384);         // 32*128*128 bf16 = 1 MB

    pool_kernel<<<dim3(B_ * CIN), 256, 0, stream>>>(x, pooled);
    gate_kernel<<<dim3(B_), 256, 0, stream>>>(pooled, gate_w, gate_b, expert_w, wmix);
    conv_kernel<<<dim3(HW_ / 64, B_), 256, 0, stream>>>(x, wmix, out);
}

// Round 4
// 133.930 us; speedup vs baseline: 1.3573x; 1.3573x over previous
//
#include <hip/hip_runtime.h>
#include <hip/hip_bf16.h>
#include <stdint.h>

#define B_    32
#define CIN   128
#define COUT  128
#define KEXP  4
#define HW_   12544   // 112*112
#define NT    4       // pixel tiles (of 64) per block

typedef __attribute__((ext_vector_type(8))) short bf16x8;
typedef __attribute__((ext_vector_type(4))) float f32x4;

// fp32 -> bf16 round-to-nearest-even (inputs finite, no NaN handling)
static __device__ __forceinline__ ushort f2bf(float f) {
    uint32_t u = __builtin_bit_cast(uint32_t, f);
    u += 0x7FFFu + ((u >> 16) & 1u);
    return (ushort)(u >> 16);
}

// ---------------------------------------------------------------------------
// Kernel 1: pooled[b][i] = mean_{hw} x[b][i][hw].  One block per (b,i) row.
// Normal (caching) loads on purpose: warms L3 with x for conv_kernel.
// ---------------------------------------------------------------------------
__global__ __launch_bounds__(256) void pool_kernel(const float* __restrict__ x,
                                                   float* __restrict__ pooled) {
    const int row = blockIdx.x;                 // b*128 + i
    const float4* __restrict__ x4 = (const float4*)(x + (size_t)row * HW_);
    const int t = threadIdx.x;
    float s = 0.f;
    for (int idx = t; idx < HW_ / 4; idx += 256) {   // 3136 float4
        float4 v = x4[idx];
        s += (v.x + v.y) + (v.z + v.w);
    }
    #pragma unroll
    for (int off = 32; off > 0; off >>= 1) s += __shfl_down(s, off, 64);
    __shared__ float wsum[4];
    if ((t & 63) == 0) wsum[t >> 6] = s;
    __syncthreads();
    if (t == 0) pooled[row] = (wsum[0] + wsum[1] + wsum[2] + wsum[3]) * (1.0f / HW_);
}

// ---------------------------------------------------------------------------
// Kernel 2: gate (softmax over K=4) + combine expert weights -> bf16 w_mix.
// One block per batch sample.
// ---------------------------------------------------------------------------
__global__ __launch_bounds__(256) void gate_kernel(const float* __restrict__ pooled,
                                                   const float* __restrict__ gate_w,
                                                   const float* __restrict__ gate_b,
                                                   const float* __restrict__ expert_w,
                                                   short* __restrict__ wmix) {
    const int b = blockIdx.x;
    const int t = threadIdx.x;
    const int wid = t >> 6, lane = t & 63;
    __shared__ float logits[KEXP];
    __shared__ float gsh[KEXP];
    {
        float p0 = pooled[b * CIN + lane];
        float p1 = pooled[b * CIN + 64 + lane];
        float s = p0 * gate_w[wid * CIN + lane] + p1 * gate_w[wid * CIN + 64 + lane];
        #pragma unroll
        for (int off = 32; off > 0; off >>= 1) s += __shfl_down(s, off, 64);
        if (lane == 0) logits[wid] = s + gate_b[wid];
    }
    __syncthreads();
    if (t == 0) {
        float m = fmaxf(fmaxf(logits[0], logits[1]), fmaxf(logits[2], logits[3]));
        float e0 = expf(logits[0] - m), e1 = expf(logits[1] - m);
        float e2 = expf(logits[2] - m), e3 = expf(logits[3] - m);
        float inv = 1.f / (e0 + e1 + e2 + e3);
        gsh[0] = e0 * inv; gsh[1] = e1 * inv; gsh[2] = e2 * inv; gsh[3] = e3 * inv;
    }
    __syncthreads();
    const float g0 = gsh[0], g1 = gsh[1], g2 = gsh[2], g3 = gsh[3];
    for (int idx = t; idx < COUT * CIN; idx += 256) {
        float w = g0 * expert_w[idx]
                + g1 * expert_w[COUT * CIN + idx]
                + g2 * expert_w[2 * COUT * CIN + idx]
                + g3 * expert_w[3 * COUT * CIN + idx];
        wmix[b * COUT * CIN + idx] = (short)f2bf(w);
    }
}

// ---------------------------------------------------------------------------
// Kernel 3: out[b] = w_mix[b] (128x128) @ x[b] (128x12544), bf16 MFMA.
// Block = 4 waves; owns NT=4 consecutive 64-px tiles (W staged ONCE).
// Pipeline per tile: prefetch loads(t+1) -> MFMA(t) -> sync -> ds_write(t+1)
// + nt-store(t) -> sync.  Both LDS tiles use a full 16-slot XOR swizzle
// (16B slot ^= row&15), write- and read-side -> uniform bank use.
// ---------------------------------------------------------------------------
__global__ __launch_bounds__(256, 4) void conv_kernel(const float* __restrict__ x,
                                                      const short* __restrict__ wmix,
                                                      float* __restrict__ out) {
    __shared__ char wlds[COUT * 256];           // 32 KB: 128 cout rows x 16 slots
    __shared__ char xlds[64 * 256];             // 16 KB: 64 pix rows x 16 slots
    const int b  = blockIdx.y;
    const int t  = threadIdx.x;
    const int base_p0 = blockIdx.x * (64 * NT);

    const int pg  = t & 15;                     // pixel 4-group
    const int cg8 = t >> 4;                     // cin octet (0..15)

    // ---- stage W once: wlds[o][slot i4 ^ (o&15)] = cins i4*8.. of cout o ----
    {
        const uint4* __restrict__ wsrc = (const uint4*)(wmix + (size_t)b * COUT * CIN);
        #pragma unroll
        for (int pass = 0; pass < 8; ++pass) {
            int o  = (t >> 4) + pass * 16;      // cout row
            int i4 = t & 15;                    // 16B slot (8 cins)
            uint4 v = wsrc[o * 16 + i4];
            *(uint4*)(wlds + o * 256 + ((i4 ^ (o & 15)) << 4)) = v;
        }
    }

    // per-thread x tile loader: 8 cin rows (cg8*8..) x 4 pixels (pg*4..)
    float4 xv[8];
    const float* __restrict__ xbase = x + (size_t)b * CIN * HW_ + (size_t)(cg8 * 8) * HW_;
    auto load_tile = [&](int p0) {
        const float* xr = xbase + p0 + pg * 4;
        #pragma unroll
        for (int i = 0; i < 8; ++i)
            xv[i] = *(const float4*)(xr + (size_t)i * HW_);
    };
    // transpose regs -> xlds[pix][slot cg8 ^ (pix&15)]
    auto write_tile = [&]() {
        #pragma unroll
        for (int j = 0; j < 4; ++j) {
            const int pix = pg * 4 + j;
            bf16x8 pk;
            #pragma unroll
            for (int i = 0; i < 8; ++i)
                pk[i] = (short)f2bf((&xv[i].x)[j]);
            *(bf16x8*)(xlds + pix * 256 + ((cg8 ^ (pix & 15)) << 4)) = pk;
        }
    };

    const int wave = t >> 6;
    const int lane = t & 63;
    const int n = lane & 15;                    // MFMA row/col within 16
    const int h = lane >> 4;                    // k-octet selector
    const int pixl = wave * 16 + n;

    load_tile(base_p0);
    write_tile();
    __syncthreads();

    for (int tt = 0; tt < NT; ++tt) {
        if (tt + 1 < NT) load_tile(base_p0 + (tt + 1) * 64);   // prefetch

        // A fragments for this tile (logical slot kk*4+h = cins kk*32+h*8)
        bf16x8 xfrag[4];
        #pragma unroll
        for (int kk = 0; kk < 4; ++kk)
            xfrag[kk] = *(const bf16x8*)(xlds + pixl * 256 + (((kk * 4 + h) ^ n) << 4));

        f32x4 acc[8];
        #pragma unroll
        for (int ot = 0; ot < 8; ++ot) acc[ot] = (f32x4){0.f, 0.f, 0.f, 0.f};

        #pragma unroll
        for (int ot = 0; ot < 8; ++ot) {
            const int o = ot * 16 + n;          // B row = cout
            #pragma unroll
            for (int kk = 0; kk < 4; ++kk) {
                bf16x8 wfrag = *(const bf16x8*)(wlds + o * 256 + (((kk * 4 + h) ^ n) << 4));
                acc[ot] = __builtin_amdgcn_mfma_f32_16x16x32_bf16(xfrag[kk], wfrag, acc[ot], 0, 0, 0);
            }
        }

        __syncthreads();                        // all waves done reading xlds(tt)
        if (tt + 1 < NT) write_tile();          // publish next tile

        // epilogue: col(lane&15)=cout, row=(lane>>4)*4+r = pixel -> f32x4 nt store
        float* __restrict__ ob = out + (size_t)b * COUT * HW_ + base_p0 + tt * 64
                               + wave * 16 + h * 4;
        #pragma unroll
        for (int ot = 0; ot < 8; ++ot)
            __builtin_nontemporal_store(acc[ot], (f32x4*)(ob + (size_t)(ot * 16 + n) * HW_));

        __syncthreads();                        // xlds(tt+1) visible
    }
}

// ---------------------------------------------------------------------------
extern "C" void kernel_launch(void* const* d_in, const int* in_sizes, int n_in,
                              void* d_out, int out_size, void* d_ws, size_t ws_size,
                              hipStream_t stream) {
    const float* x        = (const float*)d_in[0];
    const float* expert_w = (const float*)d_in[1];
    const float* gate_w   = (const float*)d_in[2];
    const float* gate_b   = (const float*)d_in[3];
    float* out = (float*)d_out;

    float* pooled = (float*)d_ws;                          // 32*128 fp32 = 16 KB
    short* wmix   = (short*)((char*)d_ws + 16384);         // 32*128*128 bf16 = 1 MB

    pool_kernel<<<dim3(B_ * CIN), 256, 0, stream>>>(x, pooled);
    gate_kernel<<<dim3(B_), 256, 0, stream>>>(pooled, gate_w, gate_b, expert_w, wmix);
    conv_kernel<<<dim3(HW_ / (64 * NT), B_), 256, 0, stream>>>(x, wmix, out);
}